// Round 7
// baseline (277.207 us; speedup 1.0000x reference)
//
#include <hip/hip_runtime.h>
#include <hip/hip_bf16.h>

typedef __attribute__((ext_vector_type(8))) short short8;
typedef __attribute__((ext_vector_type(4))) float f32x4;

__device__ __forceinline__ ushort f2bf(float f) {
    union { float f; uint u; } v; v.f = f;
    uint u = v.u;
    return (ushort)((u + 0x7fffu + ((u >> 16) & 1u)) >> 16);  // RNE
}
__device__ __forceinline__ float bf_lo(uint u) { return __uint_as_float(u << 16); }
__device__ __forceinline__ float bf_hi(uint u) { return __uint_as_float(u & 0xffff0000u); }
__device__ __forceinline__ float lane_bcast_f(float v, int j) {
    return __uint_as_float(__builtin_amdgcn_readlane(__float_as_uint(v), j));
}

// ---------------------------------------------------------------------------
// CSR build: coarse partition by dst>>8 (+fused weight cast), then per-bucket
// counting sort with inline bucket-offset scan. Edges packed (dst<<16)|src.
// ---------------------------------------------------------------------------
#define PCHUNK 4096

__global__ __launch_bounds__(256) void k_partition(const int* __restrict__ src,
                                                   const int* __restrict__ dst, int E,
                                                   int nbuck, int cap, int pblocks,
                                                   int* __restrict__ gcur,
                                                   uint* __restrict__ part,
                                                   const float* __restrict__ W1,
                                                   const float* __restrict__ W2,
                                                   const float* __restrict__ W3,
                                                   ushort* __restrict__ wt1,
                                                   ushort* __restrict__ wt2,
                                                   ushort* __restrict__ wt3) {
    __shared__ int hist[256];
    __shared__ int base[256];
    __shared__ int cnt2[256];
    const int tid = threadIdx.x;

    if ((int)blockIdx.x >= pblocks) {
        // weight-cast tail blocks: W[128][N] fp32 -> Wt[N][128] bf16
        int i = (blockIdx.x - pblocks) * 256 + tid;
        if (i < 16384) {
            int k = i >> 7, nn = i & 127;
            wt1[nn * 128 + k] = f2bf(W1[i]);
        } else if (i < 32768) {
            int j = i - 16384;
            int k = j >> 7, nn = j & 127;
            wt2[nn * 128 + k] = f2bf(W2[j]);
        } else if (i < 40960) {
            int j = i - 32768;
            int k = j >> 6, nn = j & 63;
            wt3[nn * 128 + k] = f2bf(W3[j]);
        }
        return;
    }

    const int s0 = blockIdx.x * PCHUNK;
    const int send = min(s0 + PCHUNK, E);
    hist[tid] = 0;
    cnt2[tid] = 0;
    __syncthreads();
    for (int i = s0 + tid; i < send; i += 256) {
        int d = dst[i];
        atomicAdd(&hist[d >> 8], 1);
    }
    __syncthreads();
    if (tid < nbuck && hist[tid] > 0) base[tid] = atomicAdd(&gcur[tid], hist[tid]);
    __syncthreads();
    for (int i = s0 + tid; i < send; i += 256) {
        int d = dst[i];
        int s = src[i];
        int k = d >> 8;
        int r = base[k] + atomicAdd(&cnt2[k], 1);
        if (r < cap) part[(size_t)k * cap + r] = ((uint)d << 16) | (uint)s;
    }
}

__global__ __launch_bounds__(256) void k_bucket_sort(const uint* __restrict__ part,
                                                     const int* __restrict__ gcur,
                                                     int nbuck, int cap, int n,
                                                     int* __restrict__ rowptr,
                                                     float* __restrict__ dis,
                                                     int* __restrict__ csr) {
    __shared__ int hist[256];
    __shared__ int pfx[256];
    __shared__ int sscan[256];
    const int b = blockIdx.x;
    const int tid = threadIdx.x;

    int gv = (tid < nbuck) ? min(gcur[tid], cap) : 0;
    sscan[tid] = gv;
    __syncthreads();
    for (int off = 1; off < 256; off <<= 1) {
        int t = (tid >= off) ? sscan[tid - off] : 0;
        __syncthreads();
        sscan[tid] += t;
        __syncthreads();
    }
    const int outbase = (b == 0) ? 0 : sscan[b - 1];
    const int sz = min(gcur[b], cap);
    const uint* seg = part + (size_t)b * cap;

    hist[tid] = 0;
    __syncthreads();
    for (int i = tid; i < sz; i += 256) atomicAdd(&hist[(seg[i] >> 16) & 255], 1);
    __syncthreads();

    int cnt_t = hist[tid];
    pfx[tid] = cnt_t;
    __syncthreads();
    for (int off = 1; off < 256; off <<= 1) {
        int t = (tid >= off) ? pfx[tid - off] : 0;
        __syncthreads();
        pfx[tid] += t;
        __syncthreads();
    }
    int excl = pfx[tid] - cnt_t;

    int node = b * 256 + tid;
    if (node < n) {
        rowptr[node] = outbase + excl;
        dis[node] = rsqrtf((float)(cnt_t + 1));  // +1 self loop
        if (node == n - 1) rowptr[n] = outbase + excl + cnt_t;
    }
    __syncthreads();
    pfx[tid] = excl;
    hist[tid] = 0;
    __syncthreads();
    for (int i = tid; i < sz; i += 256) {
        uint p = seg[i];
        int j = (p >> 16) & 255;
        int r = atomicAdd(&hist[j], 1);
        csr[outbase + pfx[j] + r] = (int)(p & 0xffffu);
    }
}

// ---------------------------------------------------------------------------
// bf16 MFMA GEMM: Y[n,COLS](bf16) = X[n,128] @ Wt[COLS][128](bf16)
// ---------------------------------------------------------------------------
template <int COLS, bool F32IN>
__global__ __launch_bounds__(256) void gemm_mfma(const void* __restrict__ Xin,
                                                 const ushort* __restrict__ Wt,
                                                 ushort* __restrict__ Y, int n) {
    constexpr int LDW = 136;  // +8 pad
    __shared__ ushort sX[64 * LDW];
    __shared__ ushort sW[COLS * LDW];
    const int tid = threadIdx.x;
    const int row0 = blockIdx.x * 64;

    if (F32IN) {
        const float* Xf = (const float*)Xin;
#pragma unroll
        for (int i = 0; i < 8; ++i) {
            int idx = i * 256 + tid;
            int r = idx >> 5, kc = idx & 31;
            int gr = min(row0 + r, n - 1);
            float4 v = *(const float4*)&Xf[(size_t)gr * 128 + kc * 4];
            ushort4 o;
            o.x = f2bf(v.x); o.y = f2bf(v.y); o.z = f2bf(v.z); o.w = f2bf(v.w);
            *(ushort4*)&sX[r * LDW + kc * 4] = o;
        }
    } else {
        const ushort* Xb = (const ushort*)Xin;
#pragma unroll
        for (int i = 0; i < 4; ++i) {
            int idx = i * 256 + tid;
            int r = idx >> 4, kc = idx & 15;
            int gr = min(row0 + r, n - 1);
            uint4 v = *(const uint4*)&Xb[(size_t)gr * 128 + kc * 8];
            *(uint4*)&sX[r * LDW + kc * 8] = v;
        }
    }
#pragma unroll
    for (int c = tid; c < COLS * 16; c += 256) {
        int r = c >> 4, kc = c & 15;
        uint4 v = *(const uint4*)&Wt[(size_t)r * 128 + kc * 8];
        *(uint4*)&sW[r * LDW + kc * 8] = v;
    }
    __syncthreads();

    constexpr int NT = (COLS == 128) ? 2 : 1;
    constexpr int WN = COLS / 4;
    const int w = tid >> 6;
    const int lane = tid & 63;
    const int lm = lane & 15;
    const int kq = lane >> 4;

    f32x4 acc[4][NT];
#pragma unroll
    for (int mt = 0; mt < 4; ++mt)
#pragma unroll
        for (int ntn = 0; ntn < NT; ++ntn) acc[mt][ntn] = (f32x4){0.f, 0.f, 0.f, 0.f};

#pragma unroll
    for (int ks = 0; ks < 4; ++ks) {
        const int k0 = ks * 32 + kq * 8;
        short8 bfr[NT];
#pragma unroll
        for (int ntn = 0; ntn < NT; ++ntn)
            bfr[ntn] = *(const short8*)&sW[(w * WN + ntn * 16 + lm) * LDW + k0];
#pragma unroll
        for (int mt = 0; mt < 4; ++mt) {
            short8 afr = *(const short8*)&sX[(mt * 16 + lm) * LDW + k0];
#pragma unroll
            for (int ntn = 0; ntn < NT; ++ntn)
                acc[mt][ntn] = __builtin_amdgcn_mfma_f32_16x16x32_bf16(afr, bfr[ntn], acc[mt][ntn], 0, 0, 0);
        }
    }

#pragma unroll
    for (int mt = 0; mt < 4; ++mt) {
        int r_base = row0 + mt * 16 + kq * 4;
#pragma unroll
        for (int ntn = 0; ntn < NT; ++ntn) {
            int col = w * WN + ntn * 16 + lm;
#pragma unroll
            for (int rr = 0; rr < 4; ++rr) {
                int r = r_base + rr;
                if (r < n) Y[(size_t)r * COLS + col] = f2bf(acc[mt][ntn][rr]);
            }
        }
    }
}

// ---------------------------------------------------------------------------
// agg128: out[v] = act( dv*Σ dis[s]*H[s] + dv²*H[v] + b )
// One wave/node; 32 lanes per row (uint2 = 4 bf16 cols/lane); wave halves
// process even/odd edges. readlane indices stay WAVE-UNIFORM (two broadcasts
// per pair, per-half select via cndmask) — divergent readlane is UB.
// ---------------------------------------------------------------------------
template <bool RELU>
__global__ __launch_bounds__(256) void agg128(const ushort* __restrict__ H,
                                              const float* __restrict__ dis,
                                              const int* __restrict__ rowptr,
                                              const int* __restrict__ csr,
                                              const float* __restrict__ bias,
                                              uint* __restrict__ out, int n) {
    const int wid = blockIdx.x * 4 + (threadIdx.x >> 6);
    const int lane = threadIdx.x & 63;
    if (wid >= n) return;
    const int v = wid;
    const float dv = dis[v];
    const int e0 = rowptr[v];
    const int e1 = rowptr[v + 1];
    const uint2* H2 = (const uint2*)H;  // row = 32 uint2
    const int col = lane & 31;
    const int half = lane >> 5;

    float a0 = 0.f, a1 = 0.f, a2 = 0.f, a3 = 0.f;
    int e = e0;
    while (e < e1) {
        const int c = min(e1 - e, 64);
        int sidx = 0; float sw = 0.0f;
        if (lane < c) { sidx = csr[e + lane]; sw = dis[sidx]; }
        const int P = (c + 1) >> 1;
        int p = 0;
        for (; p + 8 <= P; p += 8) {
            uint2 hv[8]; float w[8];
#pragma unroll
            for (int u = 0; u < 8; ++u) {
                const int b2 = (p + u) * 2;          // uniform
                const int cs_o = min(b2 + 1, c - 1); // uniform
                int s_e = __builtin_amdgcn_readlane(sidx, b2);
                int s_o = __builtin_amdgcn_readlane(sidx, cs_o);
                float w_e = lane_bcast_f(sw, b2);
                float w_o = lane_bcast_f(sw, cs_o);
                int s = half ? s_o : s_e;
                float ww = half ? w_o : w_e;
                w[u] = (b2 + half < c) ? ww : 0.0f;
                hv[u] = H2[(size_t)s * 32 + col];
            }
#pragma unroll
            for (int u = 0; u < 8; ++u) {
                a0 += w[u] * bf_lo(hv[u].x); a1 += w[u] * bf_hi(hv[u].x);
                a2 += w[u] * bf_lo(hv[u].y); a3 += w[u] * bf_hi(hv[u].y);
            }
        }
        for (; p < P; ++p) {
            const int b2 = p * 2;
            const int cs_o = min(b2 + 1, c - 1);
            int s_e = __builtin_amdgcn_readlane(sidx, b2);
            int s_o = __builtin_amdgcn_readlane(sidx, cs_o);
            float w_e = lane_bcast_f(sw, b2);
            float w_o = lane_bcast_f(sw, cs_o);
            int s = half ? s_o : s_e;
            float ww = half ? w_o : w_e;
            float w0 = (b2 + half < c) ? ww : 0.0f;
            uint2 hv = H2[(size_t)s * 32 + col];
            a0 += w0 * bf_lo(hv.x); a1 += w0 * bf_hi(hv.x);
            a2 += w0 * bf_lo(hv.y); a3 += w0 * bf_hi(hv.y);
        }
        e += c;
    }
    a0 += __shfl_xor(a0, 32, 64);
    a1 += __shfl_xor(a1, 32, 64);
    a2 += __shfl_xor(a2, 32, 64);
    a3 += __shfl_xor(a3, 32, 64);

    if (half == 0) {
        uint2 hs = H2[(size_t)v * 32 + col];
        float4 b = ((const float4*)bias)[col];
        float d2 = dv * dv;
        float r0 = dv * a0 + d2 * bf_lo(hs.x) + b.x;
        float r1 = dv * a1 + d2 * bf_hi(hs.x) + b.y;
        float r2 = dv * a2 + d2 * bf_lo(hs.y) + b.z;
        float r3 = dv * a3 + d2 * bf_hi(hs.y) + b.w;
        if (RELU) {
            r0 = fmaxf(r0, 0.f); r1 = fmaxf(r1, 0.f);
            r2 = fmaxf(r2, 0.f); r3 = fmaxf(r3, 0.f);
        }
        uint2 pk;
        pk.x = (uint)f2bf(r0) | ((uint)f2bf(r1) << 16);
        pk.y = (uint)f2bf(r2) | ((uint)f2bf(r3) << 16);
        ((uint2*)out)[(size_t)v * 32 + col] = pk;
    }
}

// ---------------------------------------------------------------------------
// agg64 + row-normalize (final GCN layer), with target_mlp fused as tail
// blocks. Same uniform-readlane even/odd scheme; fp32 output.
// ---------------------------------------------------------------------------
__global__ __launch_bounds__(256) void agg64_final(const ushort* __restrict__ H,
                                                   const float* __restrict__ dis,
                                                   const int* __restrict__ rowptr,
                                                   const int* __restrict__ csr,
                                                   const float* __restrict__ bias,
                                                   float* __restrict__ out, int n, int agrid,
                                                   const float* __restrict__ y,
                                                   const float* __restrict__ gamma,
                                                   const float* __restrict__ beta,
                                                   const float* __restrict__ Wm1,
                                                   const float* __restrict__ bm1,
                                                   const float* __restrict__ Wm2,
                                                   const float* __restrict__ bm2,
                                                   float* __restrict__ out_y) {
    __shared__ float red[256];
    __shared__ float t1[128];
    __shared__ float s_mu, s_var;
    const int tid = threadIdx.x;

    if ((int)blockIdx.x >= agrid) {
        // ---- target MLP tail block (one per row of y) ----
        float yv = y[tid];
        red[tid] = yv;
        __syncthreads();
        for (int s = 128; s > 0; s >>= 1) {
            if (tid < s) red[tid] += red[tid + s];
            __syncthreads();
        }
        if (tid == 0) s_mu = red[0] * (1.0f / 256.0f);
        __syncthreads();
        float mu = s_mu;
        float d = yv - mu;
        red[tid] = d * d;
        __syncthreads();
        for (int s = 128; s > 0; s >>= 1) {
            if (tid < s) red[tid] += red[tid + s];
            __syncthreads();
        }
        if (tid == 0) s_var = red[0] * (1.0f / 256.0f);
        __syncthreads();

        const int row = blockIdx.x - agrid;
        float yb = (y[row] - mu) * rsqrtf(s_var + 1e-5f) * gamma[0] + beta[0];
        if (tid < 128) t1[tid] = fmaxf(yb * Wm1[tid] + bm1[tid], 0.0f);
        __syncthreads();
        if (tid < 64) {
            float acc = bm2[tid];
#pragma unroll 8
            for (int c = 0; c < 128; ++c) acc += t1[c] * Wm2[c * 64 + tid];
            float ss = acc * acc;
#pragma unroll
            for (int m = 1; m < 64; m <<= 1) ss += __shfl_xor(ss, m, 64);
            out_y[row * 64 + tid] = acc / fmaxf(sqrtf(ss), 1e-12f);
        }
        return;
    }

    const int wid = blockIdx.x * 4 + (tid >> 6);
    const int lane = tid & 63;
    if (wid >= n) return;
    const int v = wid;
    const float dv = dis[v];
    const int e0 = rowptr[v];
    const int e1 = rowptr[v + 1];
    const uint* Hu = (const uint*)H;  // row = 32 uints
    const int col = lane & 31;
    const int half = lane >> 5;

    float a0 = 0.f, a1 = 0.f;
    int e = e0;
    while (e < e1) {
        const int c = min(e1 - e, 64);
        int sidx = 0; float sw = 0.0f;
        if (lane < c) { sidx = csr[e + lane]; sw = dis[sidx]; }
        const int P = (c + 1) >> 1;
        int p = 0;
        for (; p + 8 <= P; p += 8) {
            uint hv[8]; float w[8];
#pragma unroll
            for (int u = 0; u < 8; ++u) {
                const int b2 = (p + u) * 2;
                const int cs_o = min(b2 + 1, c - 1);
                int s_e = __builtin_amdgcn_readlane(sidx, b2);
                int s_o = __builtin_amdgcn_readlane(sidx, cs_o);
                float w_e = lane_bcast_f(sw, b2);
                float w_o = lane_bcast_f(sw, cs_o);
                int s = half ? s_o : s_e;
                float ww = half ? w_o : w_e;
                w[u] = (b2 + half < c) ? ww : 0.0f;
                hv[u] = Hu[(size_t)s * 32 + col];
            }
#pragma unroll
            for (int u = 0; u < 8; ++u) {
                a0 += w[u] * bf_lo(hv[u]); a1 += w[u] * bf_hi(hv[u]);
            }
        }
        for (; p < P; ++p) {
            const int b2 = p * 2;
            const int cs_o = min(b2 + 1, c - 1);
            int s_e = __builtin_amdgcn_readlane(sidx, b2);
            int s_o = __builtin_amdgcn_readlane(sidx, cs_o);
            float w_e = lane_bcast_f(sw, b2);
            float w_o = lane_bcast_f(sw, cs_o);
            int s = half ? s_o : s_e;
            float ww = half ? w_o : w_e;
            float w0 = (b2 + half < c) ? ww : 0.0f;
            uint hv = Hu[(size_t)s * 32 + col];
            a0 += w0 * bf_lo(hv); a1 += w0 * bf_hi(hv);
        }
        e += c;
    }
    a0 += __shfl_xor(a0, 32, 64);
    a1 += __shfl_xor(a1, 32, 64);

    if (half == 0) {
        uint hs = Hu[(size_t)v * 32 + col];
        float2 b = ((const float2*)bias)[col];
        float d2 = dv * dv;
        float r0 = dv * a0 + d2 * bf_lo(hs) + b.x;
        float r1 = dv * a1 + d2 * bf_hi(hs) + b.y;
        float ss = r0 * r0 + r1 * r1;
#pragma unroll
        for (int m = 1; m < 32; m <<= 1) ss += __shfl_xor(ss, m, 64);
        float inv = 1.0f / fmaxf(sqrtf(ss), 1e-12f);
        float2 o = make_float2(r0 * inv, r1 * inv);
        ((float2*)out)[(size_t)v * 32 + col] = o;
    }
}

// ---------------------------------------------------------------------------
extern "C" void kernel_launch(void* const* d_in, const int* in_sizes, int n_in,
                              void* d_out, int out_size, void* d_ws, size_t ws_size,
                              hipStream_t stream) {
    const float* x     = (const float*)d_in[0];
    const float* y     = (const float*)d_in[1];
    const int*   edge  = (const int*)d_in[2];
    const float* W1    = (const float*)d_in[3];
    const float* b1    = (const float*)d_in[4];
    const float* W2    = (const float*)d_in[5];
    const float* b2    = (const float*)d_in[6];
    const float* W3    = (const float*)d_in[7];
    const float* b3    = (const float*)d_in[8];
    const float* bng   = (const float*)d_in[9];
    const float* bnb   = (const float*)d_in[10];
    const float* Wm1   = (const float*)d_in[11];
    const float* bm1   = (const float*)d_in[12];
    const float* Wm2   = (const float*)d_in[13];
    const float* bm2   = (const float*)d_in[14];

    const int n = in_sizes[0] / 128;  // 50000
    const int E = in_sizes[2] / 2;    // 800000
    const int* src = edge;
    const int* dst = edge + E;

    const int nbuck = (n + 255) / 256;                 // 196
    const int cap = E / nbuck + E / nbuck / 4 + 1024;  // mean + 25% + slack

    size_t off = 0;
    auto carve = [&](size_t bytes) {
        size_t p = off;
        off = (off + bytes + 255) & ~(size_t)255;
        return p;
    };
    char* ws = (char*)d_ws;
    int*    gcur    = (int*)(ws + carve(256 * 4));
    uint*   part    = (uint*)(ws + carve((size_t)nbuck * cap * 4));
    int*    rowptr  = (int*)(ws + carve((size_t)(n + 1) * 4));
    int*    csr     = (int*)(ws + carve((size_t)E * 4));
    float*  dis     = (float*)(ws + carve((size_t)n * 4));
    ushort* wt1     = (ushort*)(ws + carve(128 * 128 * 2));
    ushort* wt2     = (ushort*)(ws + carve(128 * 128 * 2));
    ushort* wt3     = (ushort*)(ws + carve(64 * 128 * 2));
    ushort* bufA    = (ushort*)(ws + carve((size_t)n * 128 * 2));
    ushort* bufB    = (ushort*)(ws + carve((size_t)n * 128 * 2));
    ushort* bufC    = (ushort*)(ws + carve((size_t)n * 64 * 2));
    (void)ws_size; (void)n_in; (void)out_size;

    float* x_emb = (float*)d_out;
    float* y_emb = (float*)d_out + (size_t)n * 64;

    const int pblocks = (E + PCHUNK - 1) / PCHUNK;  // 196

    hipMemsetAsync(gcur, 0, 256 * 4, stream);
    k_partition<<<pblocks + 160, 256, 0, stream>>>(src, dst, E, nbuck, cap, pblocks,
                                                   gcur, part, W1, W2, W3, wt1, wt2, wt3);
    k_bucket_sort<<<nbuck, 256, 0, stream>>>(part, gcur, nbuck, cap, n, rowptr, dis, csr);

    const int ggrid = (n + 63) / 64;
    const int agrid = (n + 3) / 4;

    gemm_mfma<128, true><<<ggrid, 256, 0, stream>>>(x, wt1, bufA, n);
    agg128<true><<<agrid, 256, 0, stream>>>(bufA, dis, rowptr, csr, b1, (uint*)bufB, n);
    gemm_mfma<128, false><<<ggrid, 256, 0, stream>>>(bufB, wt2, bufA, n);
    agg128<true><<<agrid, 256, 0, stream>>>(bufA, dis, rowptr, csr, b2, (uint*)bufB, n);
    gemm_mfma<64, false><<<ggrid, 256, 0, stream>>>(bufB, wt3, bufC, n);
    agg64_final<<<agrid + 256, 256, 0, stream>>>(bufC, dis, rowptr, csr, b3, x_emb, n, agrid,
                                                 y, bng, bnb, Wm1, bm1, Wm2, bm2, y_emb);
}

// Round 8
// 259.302 us; speedup vs baseline: 1.0690x; 1.0690x over previous
//
#include <hip/hip_runtime.h>
#include <hip/hip_bf16.h>

typedef __attribute__((ext_vector_type(8))) short short8;
typedef __attribute__((ext_vector_type(4))) float f32x4;

__device__ __forceinline__ ushort f2bf(float f) {
    union { float f; uint u; } v; v.f = f;
    uint u = v.u;
    return (ushort)((u + 0x7fffu + ((u >> 16) & 1u)) >> 16);  // RNE
}
__device__ __forceinline__ float bf_lo(uint u) { return __uint_as_float(u << 16); }
__device__ __forceinline__ float bf_hi(uint u) { return __uint_as_float(u & 0xffff0000u); }
__device__ __forceinline__ float lane_bcast_f(float v, int j) {
    return __uint_as_float(__builtin_amdgcn_readlane(__float_as_uint(v), j));
}

// ---------------------------------------------------------------------------
// CSR build: coarse partition by dst>>8 (+fused weight cast), then per-bucket
// counting sort with inline bucket-offset scan. Edges packed (dst<<16)|src.
// ---------------------------------------------------------------------------
#define PCHUNK 4096

__global__ __launch_bounds__(256) void k_partition(const int* __restrict__ src,
                                                   const int* __restrict__ dst, int E,
                                                   int nbuck, int cap, int pblocks,
                                                   int* __restrict__ gcur,
                                                   uint* __restrict__ part,
                                                   const float* __restrict__ W1,
                                                   const float* __restrict__ W2,
                                                   const float* __restrict__ W3,
                                                   ushort* __restrict__ wt1,
                                                   ushort* __restrict__ wt2,
                                                   ushort* __restrict__ wt3) {
    __shared__ int hist[256];
    __shared__ int base[256];
    __shared__ int cnt2[256];
    const int tid = threadIdx.x;

    if ((int)blockIdx.x >= pblocks) {
        // weight-cast tail blocks: W[128][N] fp32 -> Wt[N][128] bf16
        int i = (blockIdx.x - pblocks) * 256 + tid;
        if (i < 16384) {
            int k = i >> 7, nn = i & 127;
            wt1[nn * 128 + k] = f2bf(W1[i]);
        } else if (i < 32768) {
            int j = i - 16384;
            int k = j >> 7, nn = j & 127;
            wt2[nn * 128 + k] = f2bf(W2[j]);
        } else if (i < 40960) {
            int j = i - 32768;
            int k = j >> 6, nn = j & 63;
            wt3[nn * 128 + k] = f2bf(W3[j]);
        }
        return;
    }

    const int s0 = blockIdx.x * PCHUNK;
    const int send = min(s0 + PCHUNK, E);
    hist[tid] = 0;
    cnt2[tid] = 0;
    __syncthreads();
    for (int i = s0 + tid; i < send; i += 256) {
        int d = dst[i];
        atomicAdd(&hist[d >> 8], 1);
    }
    __syncthreads();
    if (tid < nbuck && hist[tid] > 0) base[tid] = atomicAdd(&gcur[tid], hist[tid]);
    __syncthreads();
    for (int i = s0 + tid; i < send; i += 256) {
        int d = dst[i];
        int s = src[i];
        int k = d >> 8;
        int r = base[k] + atomicAdd(&cnt2[k], 1);
        if (r < cap) part[(size_t)k * cap + r] = ((uint)d << 16) | (uint)s;
    }
}

__global__ __launch_bounds__(256) void k_bucket_sort(const uint* __restrict__ part,
                                                     const int* __restrict__ gcur,
                                                     int nbuck, int cap, int n,
                                                     int* __restrict__ rowptr,
                                                     float* __restrict__ dis,
                                                     int* __restrict__ csr) {
    __shared__ int hist[256];
    __shared__ int pfx[256];
    __shared__ int sscan[256];
    const int b = blockIdx.x;
    const int tid = threadIdx.x;

    int gv = (tid < nbuck) ? min(gcur[tid], cap) : 0;
    sscan[tid] = gv;
    __syncthreads();
    for (int off = 1; off < 256; off <<= 1) {
        int t = (tid >= off) ? sscan[tid - off] : 0;
        __syncthreads();
        sscan[tid] += t;
        __syncthreads();
    }
    const int outbase = (b == 0) ? 0 : sscan[b - 1];
    const int sz = min(gcur[b], cap);
    const uint* seg = part + (size_t)b * cap;

    hist[tid] = 0;
    __syncthreads();
    for (int i = tid; i < sz; i += 256) atomicAdd(&hist[(seg[i] >> 16) & 255], 1);
    __syncthreads();

    int cnt_t = hist[tid];
    pfx[tid] = cnt_t;
    __syncthreads();
    for (int off = 1; off < 256; off <<= 1) {
        int t = (tid >= off) ? pfx[tid - off] : 0;
        __syncthreads();
        pfx[tid] += t;
        __syncthreads();
    }
    int excl = pfx[tid] - cnt_t;

    int node = b * 256 + tid;
    if (node < n) {
        rowptr[node] = outbase + excl;
        dis[node] = rsqrtf((float)(cnt_t + 1));  // +1 self loop
        if (node == n - 1) rowptr[n] = outbase + excl + cnt_t;
    }
    __syncthreads();
    pfx[tid] = excl;
    hist[tid] = 0;
    __syncthreads();
    for (int i = tid; i < sz; i += 256) {
        uint p = seg[i];
        int j = (p >> 16) & 255;
        int r = atomicAdd(&hist[j], 1);
        csr[outbase + pfx[j] + r] = (int)(p & 0xffffu);
    }
}

// ---------------------------------------------------------------------------
// bf16 MFMA GEMM: Y[n,COLS](bf16) = X[n,128] @ Wt[COLS][128](bf16)
// ---------------------------------------------------------------------------
template <int COLS, bool F32IN>
__global__ __launch_bounds__(256) void gemm_mfma(const void* __restrict__ Xin,
                                                 const ushort* __restrict__ Wt,
                                                 ushort* __restrict__ Y, int n) {
    constexpr int LDW = 136;  // +8 pad
    __shared__ ushort sX[64 * LDW];
    __shared__ ushort sW[COLS * LDW];
    const int tid = threadIdx.x;
    const int row0 = blockIdx.x * 64;

    if (F32IN) {
        const float* Xf = (const float*)Xin;
#pragma unroll
        for (int i = 0; i < 8; ++i) {
            int idx = i * 256 + tid;
            int r = idx >> 5, kc = idx & 31;
            int gr = min(row0 + r, n - 1);
            float4 v = *(const float4*)&Xf[(size_t)gr * 128 + kc * 4];
            ushort4 o;
            o.x = f2bf(v.x); o.y = f2bf(v.y); o.z = f2bf(v.z); o.w = f2bf(v.w);
            *(ushort4*)&sX[r * LDW + kc * 4] = o;
        }
    } else {
        const ushort* Xb = (const ushort*)Xin;
#pragma unroll
        for (int i = 0; i < 4; ++i) {
            int idx = i * 256 + tid;
            int r = idx >> 4, kc = idx & 15;
            int gr = min(row0 + r, n - 1);
            uint4 v = *(const uint4*)&Xb[(size_t)gr * 128 + kc * 8];
            *(uint4*)&sX[r * LDW + kc * 8] = v;
        }
    }
#pragma unroll
    for (int c = tid; c < COLS * 16; c += 256) {
        int r = c >> 4, kc = c & 15;
        uint4 v = *(const uint4*)&Wt[(size_t)r * 128 + kc * 8];
        *(uint4*)&sW[r * LDW + kc * 8] = v;
    }
    __syncthreads();

    constexpr int NT = (COLS == 128) ? 2 : 1;
    constexpr int WN = COLS / 4;
    const int w = tid >> 6;
    const int lane = tid & 63;
    const int lm = lane & 15;
    const int kq = lane >> 4;

    f32x4 acc[4][NT];
#pragma unroll
    for (int mt = 0; mt < 4; ++mt)
#pragma unroll
        for (int ntn = 0; ntn < NT; ++ntn) acc[mt][ntn] = (f32x4){0.f, 0.f, 0.f, 0.f};

#pragma unroll
    for (int ks = 0; ks < 4; ++ks) {
        const int k0 = ks * 32 + kq * 8;
        short8 bfr[NT];
#pragma unroll
        for (int ntn = 0; ntn < NT; ++ntn)
            bfr[ntn] = *(const short8*)&sW[(w * WN + ntn * 16 + lm) * LDW + k0];
#pragma unroll
        for (int mt = 0; mt < 4; ++mt) {
            short8 afr = *(const short8*)&sX[(mt * 16 + lm) * LDW + k0];
#pragma unroll
            for (int ntn = 0; ntn < NT; ++ntn)
                acc[mt][ntn] = __builtin_amdgcn_mfma_f32_16x16x32_bf16(afr, bfr[ntn], acc[mt][ntn], 0, 0, 0);
        }
    }

#pragma unroll
    for (int mt = 0; mt < 4; ++mt) {
        int r_base = row0 + mt * 16 + kq * 4;
#pragma unroll
        for (int ntn = 0; ntn < NT; ++ntn) {
            int col = w * WN + ntn * 16 + lm;
#pragma unroll
            for (int rr = 0; rr < 4; ++rr) {
                int r = r_base + rr;
                if (r < n) Y[(size_t)r * COLS + col] = f2bf(acc[mt][ntn][rr]);
            }
        }
    }
}

// ---------------------------------------------------------------------------
// agg128: out[v] = act( dv*(Σ dis[s]*H[s] + dv*H[v]) + b )
// One wave/node; 64 lanes per row (uint = 2 bf16 cols/lane). Edge index is
// wave-uniform (readlane -> SGPR) so row gathers use scalar base addressing.
// 16 independent gathers in flight.
// ---------------------------------------------------------------------------
template <bool RELU>
__global__ __launch_bounds__(256) void agg128(const ushort* __restrict__ H,
                                              const float* __restrict__ dis,
                                              const int* __restrict__ rowptr,
                                              const int* __restrict__ csr,
                                              const float* __restrict__ bias,
                                              uint* __restrict__ out, int n) {
    const int wid = blockIdx.x * 4 + (threadIdx.x >> 6);
    const int lane = threadIdx.x & 63;
    if (wid >= n) return;
    const int v = wid;
    const float dv = dis[v];
    const int e0 = rowptr[v];
    const int e1 = rowptr[v + 1];

    const uint* Hu = (const uint*)H;  // row = 64 uints
    uint h0 = Hu[(size_t)v * 64 + lane];
    float ax = dv * bf_lo(h0), ay = dv * bf_hi(h0);

    int e = e0;
    while (e < e1) {
        const int c = min(e1 - e, 64);
        int sidx = 0; float sw = 0.0f;
        if (lane < c) { sidx = csr[e + lane]; sw = dis[sidx]; }
        int j = 0;
        for (; j + 16 <= c; j += 16) {
            uint hv[16]; float w[16];
#pragma unroll
            for (int u = 0; u < 16; ++u) {
                int s = __builtin_amdgcn_readlane(sidx, j + u);
                w[u] = lane_bcast_f(sw, j + u);
                hv[u] = Hu[(size_t)s * 64 + lane];
            }
#pragma unroll
            for (int u = 0; u < 16; ++u) { ax += w[u] * bf_lo(hv[u]); ay += w[u] * bf_hi(hv[u]); }
        }
        for (; j + 4 <= c; j += 4) {
            uint hv[4]; float w[4];
#pragma unroll
            for (int u = 0; u < 4; ++u) {
                int s = __builtin_amdgcn_readlane(sidx, j + u);
                w[u] = lane_bcast_f(sw, j + u);
                hv[u] = Hu[(size_t)s * 64 + lane];
            }
#pragma unroll
            for (int u = 0; u < 4; ++u) { ax += w[u] * bf_lo(hv[u]); ay += w[u] * bf_hi(hv[u]); }
        }
        for (; j < c; ++j) {
            int s = __builtin_amdgcn_readlane(sidx, j);
            float w = lane_bcast_f(sw, j);
            uint hh = Hu[(size_t)s * 64 + lane];
            ax += w * bf_lo(hh); ay += w * bf_hi(hh);
        }
        e += c;
    }

    float2 b = ((const float2*)bias)[lane];
    float rx = dv * ax + b.x;
    float ry = dv * ay + b.y;
    if (RELU) { rx = fmaxf(rx, 0.f); ry = fmaxf(ry, 0.f); }
    uint packed = (uint)f2bf(rx) | ((uint)f2bf(ry) << 16);
    out[(size_t)v * 64 + lane] = packed;
}

// ---------------------------------------------------------------------------
// agg64 + row-normalize (final GCN layer), target_mlp fused as tail blocks.
// 64 lanes per row (ushort = 1 bf16 col/lane), uniform readlane, fp32 out.
// ---------------------------------------------------------------------------
__global__ __launch_bounds__(256) void agg64_final(const ushort* __restrict__ H,
                                                   const float* __restrict__ dis,
                                                   const int* __restrict__ rowptr,
                                                   const int* __restrict__ csr,
                                                   const float* __restrict__ bias,
                                                   float* __restrict__ out, int n, int agrid,
                                                   const float* __restrict__ y,
                                                   const float* __restrict__ gamma,
                                                   const float* __restrict__ beta,
                                                   const float* __restrict__ Wm1,
                                                   const float* __restrict__ bm1,
                                                   const float* __restrict__ Wm2,
                                                   const float* __restrict__ bm2,
                                                   float* __restrict__ out_y) {
    __shared__ float red[256];
    __shared__ float t1[128];
    __shared__ float s_mu, s_var;
    const int tid = threadIdx.x;

    if ((int)blockIdx.x >= agrid) {
        // ---- target MLP tail block (one per row of y) ----
        float yv = y[tid];
        red[tid] = yv;
        __syncthreads();
        for (int s = 128; s > 0; s >>= 1) {
            if (tid < s) red[tid] += red[tid + s];
            __syncthreads();
        }
        if (tid == 0) s_mu = red[0] * (1.0f / 256.0f);
        __syncthreads();
        float mu = s_mu;
        float d = yv - mu;
        red[tid] = d * d;
        __syncthreads();
        for (int s = 128; s > 0; s >>= 1) {
            if (tid < s) red[tid] += red[tid + s];
            __syncthreads();
        }
        if (tid == 0) s_var = red[0] * (1.0f / 256.0f);
        __syncthreads();

        const int row = blockIdx.x - agrid;
        float yb = (y[row] - mu) * rsqrtf(s_var + 1e-5f) * gamma[0] + beta[0];
        if (tid < 128) t1[tid] = fmaxf(yb * Wm1[tid] + bm1[tid], 0.0f);
        __syncthreads();
        if (tid < 64) {
            float acc = bm2[tid];
#pragma unroll 8
            for (int c = 0; c < 128; ++c) acc += t1[c] * Wm2[c * 64 + tid];
            float ss = acc * acc;
#pragma unroll
            for (int m = 1; m < 64; m <<= 1) ss += __shfl_xor(ss, m, 64);
            out_y[row * 64 + tid] = acc / fmaxf(sqrtf(ss), 1e-12f);
        }
        return;
    }

    const int wid = blockIdx.x * 4 + (tid >> 6);
    const int lane = tid & 63;
    if (wid >= n) return;
    const int v = wid;
    const float dv = dis[v];
    const int e0 = rowptr[v];
    const int e1 = rowptr[v + 1];

    float acc = dv * bf_lo((uint)H[(size_t)v * 64 + lane]);

    int e = e0;
    while (e < e1) {
        const int c = min(e1 - e, 64);
        int sidx = 0; float sw = 0.0f;
        if (lane < c) { sidx = csr[e + lane]; sw = dis[sidx]; }
        int j = 0;
        for (; j + 16 <= c; j += 16) {
            ushort hv[16]; float w[16];
#pragma unroll
            for (int u = 0; u < 16; ++u) {
                int s = __builtin_amdgcn_readlane(sidx, j + u);
                w[u] = lane_bcast_f(sw, j + u);
                hv[u] = H[(size_t)s * 64 + lane];
            }
#pragma unroll
            for (int u = 0; u < 16; ++u) acc += w[u] * bf_lo((uint)hv[u]);
        }
        for (; j < c; ++j) {
            int s = __builtin_amdgcn_readlane(sidx, j);
            float w = lane_bcast_f(sw, j);
            acc += w * bf_lo((uint)H[(size_t)s * 64 + lane]);
        }
        e += c;
    }

    float r = dv * acc + bias[lane];
    float ss = r * r;
#pragma unroll
    for (int m = 1; m < 64; m <<= 1) ss += __shfl_xor(ss, m, 64);
    r = r / fmaxf(sqrtf(ss), 1e-12f);
    out[(size_t)v * 64 + lane] = r;
}

// ---------------------------------------------------------------------------
extern "C" void kernel_launch(void* const* d_in, const int* in_sizes, int n_in,
                              void* d_out, int out_size, void* d_ws, size_t ws_size,
                              hipStream_t stream) {
    const float* x     = (const float*)d_in[0];
    const float* y     = (const float*)d_in[1];
    const int*   edge  = (const int*)d_in[2];
    const float* W1    = (const float*)d_in[3];
    const float* b1    = (const float*)d_in[4];
    const float* W2    = (const float*)d_in[5];
    const float* b2    = (const float*)d_in[6];
    const float* W3    = (const float*)d_in[7];
    const float* b3    = (const float*)d_in[8];
    const float* bng   = (const float*)d_in[9];
    const float* bnb   = (const float*)d_in[10];
    const float* Wm1   = (const float*)d_in[11];
    const float* bm1   = (const float*)d_in[12];
    const float* Wm2   = (const float*)d_in[13];
    const float* bm2   = (const float*)d_in[14];

    const int n = in_sizes[0] / 128;  // 50000
    const int E = in_sizes[2] / 2;    // 800000
    const int* src = edge;
    const int* dst = edge + E;

    const int nbuck = (n + 255) / 256;                 // 196
    const int cap = E / nbuck + E / nbuck / 4 + 1024;  // mean + 25% + slack

    size_t off = 0;
    auto carve = [&](size_t bytes) {
        size_t p = off;
        off = (off + bytes + 255) & ~(size_t)255;
        return p;
    };
    char* ws = (char*)d_ws;
    int*    gcur    = (int*)(ws + carve(256 * 4));
    uint*   part    = (uint*)(ws + carve((size_t)nbuck * cap * 4));
    int*    rowptr  = (int*)(ws + carve((size_t)(n + 1) * 4));
    int*    csr     = (int*)(ws + carve((size_t)E * 4));
    float*  dis     = (float*)(ws + carve((size_t)n * 4));
    ushort* wt1     = (ushort*)(ws + carve(128 * 128 * 2));
    ushort* wt2     = (ushort*)(ws + carve(128 * 128 * 2));
    ushort* wt3     = (ushort*)(ws + carve(64 * 128 * 2));
    ushort* bufA    = (ushort*)(ws + carve((size_t)n * 128 * 2));
    ushort* bufB    = (ushort*)(ws + carve((size_t)n * 128 * 2));
    ushort* bufC    = (ushort*)(ws + carve((size_t)n * 64 * 2));
    (void)ws_size; (void)n_in; (void)out_size;

    float* x_emb = (float*)d_out;
    float* y_emb = (float*)d_out + (size_t)n * 64;

    const int pblocks = (E + PCHUNK - 1) / PCHUNK;  // 196

    hipMemsetAsync(gcur, 0, 256 * 4, stream);
    k_partition<<<pblocks + 160, 256, 0, stream>>>(src, dst, E, nbuck, cap, pblocks,
                                                   gcur, part, W1, W2, W3, wt1, wt2, wt3);
    k_bucket_sort<<<nbuck, 256, 0, stream>>>(part, gcur, nbuck, cap, n, rowptr, dis, csr);

    const int ggrid = (n + 63) / 64;
    const int agrid = (n + 3) / 4;

    gemm_mfma<128, true><<<ggrid, 256, 0, stream>>>(x, wt1, bufA, n);
    agg128<true><<<agrid, 256, 0, stream>>>(bufA, dis, rowptr, csr, b1, (uint*)bufB, n);
    gemm_mfma<128, false><<<ggrid, 256, 0, stream>>>(bufB, wt2, bufA, n);
    agg128<true><<<agrid, 256, 0, stream>>>(bufA, dis, rowptr, csr, b2, (uint*)bufB, n);
    gemm_mfma<64, false><<<ggrid, 256, 0, stream>>>(bufB, wt3, bufC, n);
    agg64_final<<<agrid + 256, 256, 0, stream>>>(bufC, dis, rowptr, csr, b3, x_emb, n, agrid,
                                                 y, bng, bnb, Wm1, bm1, Wm2, bm2, y_emb);
}

// Round 9
// 247.946 us; speedup vs baseline: 1.1180x; 1.0458x over previous
//
#include <hip/hip_runtime.h>
#include <hip/hip_bf16.h>

typedef __attribute__((ext_vector_type(8))) short short8;
typedef __attribute__((ext_vector_type(4))) float f32x4;

__device__ __forceinline__ ushort f2bf(float f) {
    union { float f; uint u; } v; v.f = f;
    uint u = v.u;
    return (ushort)((u + 0x7fffu + ((u >> 16) & 1u)) >> 16);  // RNE
}
__device__ __forceinline__ float bf_lo(uint u) { return __uint_as_float(u << 16); }
__device__ __forceinline__ float bf_hi(uint u) { return __uint_as_float(u & 0xffff0000u); }
__device__ __forceinline__ float lane_bcast_f(float v, int j) {
    return __uint_as_float(__builtin_amdgcn_readlane(__float_as_uint(v), j));
}

// ---------------------------------------------------------------------------
// bf16 MFMA GEMM body: Y[n,COLS](bf16) = X[n,128] @ Wt[COLS][128](bf16)
// smem must be >= (64 + COLS) * 136 * 2 bytes.
// ---------------------------------------------------------------------------
template <int COLS, bool F32IN>
__device__ __forceinline__ void gemm_body(const void* __restrict__ Xin,
                                          const ushort* __restrict__ Wt,
                                          ushort* __restrict__ Y, int n,
                                          int bid, char* smem) {
    constexpr int LDW = 136;  // +8 pad
    ushort* sX = (ushort*)smem;
    ushort* sW = sX + 64 * LDW;
    const int tid = threadIdx.x;
    const int row0 = bid * 64;

    if (F32IN) {
        const float* Xf = (const float*)Xin;
#pragma unroll
        for (int i = 0; i < 8; ++i) {
            int idx = i * 256 + tid;
            int r = idx >> 5, kc = idx & 31;
            int gr = min(row0 + r, n - 1);
            float4 v = *(const float4*)&Xf[(size_t)gr * 128 + kc * 4];
            ushort4 o;
            o.x = f2bf(v.x); o.y = f2bf(v.y); o.z = f2bf(v.z); o.w = f2bf(v.w);
            *(ushort4*)&sX[r * LDW + kc * 4] = o;
        }
    } else {
        const ushort* Xb = (const ushort*)Xin;
#pragma unroll
        for (int i = 0; i < 4; ++i) {
            int idx = i * 256 + tid;
            int r = idx >> 4, kc = idx & 15;
            int gr = min(row0 + r, n - 1);
            uint4 v = *(const uint4*)&Xb[(size_t)gr * 128 + kc * 8];
            *(uint4*)&sX[r * LDW + kc * 8] = v;
        }
    }
#pragma unroll
    for (int c = tid; c < COLS * 16; c += 256) {
        int r = c >> 4, kc = c & 15;
        uint4 v = *(const uint4*)&Wt[(size_t)r * 128 + kc * 8];
        *(uint4*)&sW[r * LDW + kc * 8] = v;
    }
    __syncthreads();

    constexpr int NT = (COLS == 128) ? 2 : 1;
    constexpr int WN = COLS / 4;
    const int w = tid >> 6;
    const int lane = tid & 63;
    const int lm = lane & 15;
    const int kq = lane >> 4;

    f32x4 acc[4][NT];
#pragma unroll
    for (int mt = 0; mt < 4; ++mt)
#pragma unroll
        for (int ntn = 0; ntn < NT; ++ntn) acc[mt][ntn] = (f32x4){0.f, 0.f, 0.f, 0.f};

#pragma unroll
    for (int ks = 0; ks < 4; ++ks) {
        const int k0 = ks * 32 + kq * 8;
        short8 bfr[NT];
#pragma unroll
        for (int ntn = 0; ntn < NT; ++ntn)
            bfr[ntn] = *(const short8*)&sW[(w * WN + ntn * 16 + lm) * LDW + k0];
#pragma unroll
        for (int mt = 0; mt < 4; ++mt) {
            short8 afr = *(const short8*)&sX[(mt * 16 + lm) * LDW + k0];
#pragma unroll
            for (int ntn = 0; ntn < NT; ++ntn)
                acc[mt][ntn] = __builtin_amdgcn_mfma_f32_16x16x32_bf16(afr, bfr[ntn], acc[mt][ntn], 0, 0, 0);
        }
    }

#pragma unroll
    for (int mt = 0; mt < 4; ++mt) {
        int r_base = row0 + mt * 16 + kq * 4;
#pragma unroll
        for (int ntn = 0; ntn < NT; ++ntn) {
            int col = w * WN + ntn * 16 + lm;
#pragma unroll
            for (int rr = 0; rr < 4; ++rr) {
                int r = r_base + rr;
                if (r < n) Y[(size_t)r * COLS + col] = f2bf(acc[mt][ntn][rr]);
            }
        }
    }
}

// ---------------------------------------------------------------------------
// CSR build phase 1: coarse partition by dst>>8 (+fused weight cast tail).
// Edges packed (dst<<16)|src.
// ---------------------------------------------------------------------------
#define PCHUNK 4096

__global__ __launch_bounds__(256) void k_partition(const int* __restrict__ src,
                                                   const int* __restrict__ dst, int E,
                                                   int nbuck, int cap, int pblocks,
                                                   int* __restrict__ gcur,
                                                   uint* __restrict__ part,
                                                   const float* __restrict__ W1,
                                                   const float* __restrict__ W2,
                                                   const float* __restrict__ W3,
                                                   ushort* __restrict__ wt1,
                                                   ushort* __restrict__ wt2,
                                                   ushort* __restrict__ wt3) {
    __shared__ int hist[256];
    __shared__ int base[256];
    __shared__ int cnt2[256];
    const int tid = threadIdx.x;

    if ((int)blockIdx.x >= pblocks) {
        int i = (blockIdx.x - pblocks) * 256 + tid;
        if (i < 16384) {
            int k = i >> 7, nn = i & 127;
            wt1[nn * 128 + k] = f2bf(W1[i]);
        } else if (i < 32768) {
            int j = i - 16384;
            int k = j >> 7, nn = j & 127;
            wt2[nn * 128 + k] = f2bf(W2[j]);
        } else if (i < 40960) {
            int j = i - 32768;
            int k = j >> 6, nn = j & 63;
            wt3[nn * 128 + k] = f2bf(W3[j]);
        }
        return;
    }

    const int s0 = blockIdx.x * PCHUNK;
    const int send = min(s0 + PCHUNK, E);
    hist[tid] = 0;
    cnt2[tid] = 0;
    __syncthreads();
    for (int i = s0 + tid; i < send; i += 256) {
        int d = dst[i];
        atomicAdd(&hist[d >> 8], 1);
    }
    __syncthreads();
    if (tid < nbuck && hist[tid] > 0) base[tid] = atomicAdd(&gcur[tid], hist[tid]);
    __syncthreads();
    for (int i = s0 + tid; i < send; i += 256) {
        int d = dst[i];
        int s = src[i];
        int k = d >> 8;
        int r = base[k] + atomicAdd(&cnt2[k], 1);
        if (r < cap) part[(size_t)k * cap + r] = ((uint)d << 16) | (uint)s;
    }
}

// ---------------------------------------------------------------------------
// CSR build phase 2 (+fused GEMM1 tail blocks, which only depend on x/wt1).
// Blocks [0,nbuck): per-bucket counting sort -> rowptr, dis, csr.
// Blocks [nbuck, nbuck+ggrid): gemm1 (x fp32 -> bufA bf16).
// ---------------------------------------------------------------------------
__global__ __launch_bounds__(256) void k_sort_gemm1(const uint* __restrict__ part,
                                                    const int* __restrict__ gcur,
                                                    int nbuck, int cap, int n,
                                                    int* __restrict__ rowptr,
                                                    float* __restrict__ dis,
                                                    int* __restrict__ csr,
                                                    const float* __restrict__ x,
                                                    const ushort* __restrict__ wt1,
                                                    ushort* __restrict__ bufA) {
    __shared__ char smem[(64 + 128) * 136 * 2];  // 52.2 KB union
    const int tid = threadIdx.x;

    if ((int)blockIdx.x >= nbuck) {
        gemm_body<128, true>(x, wt1, bufA, n, blockIdx.x - nbuck, smem);
        return;
    }

    int* hist  = (int*)smem;          // 256 ints
    int* pfx   = hist + 256;
    int* sscan = pfx + 256;
    const int b = blockIdx.x;

    int gv = (tid < nbuck) ? min(gcur[tid], cap) : 0;
    sscan[tid] = gv;
    __syncthreads();
    for (int off = 1; off < 256; off <<= 1) {
        int t = (tid >= off) ? sscan[tid - off] : 0;
        __syncthreads();
        sscan[tid] += t;
        __syncthreads();
    }
    const int outbase = (b == 0) ? 0 : sscan[b - 1];
    const int sz = min(gcur[b], cap);
    const uint* seg = part + (size_t)b * cap;

    hist[tid] = 0;
    __syncthreads();
    for (int i = tid; i < sz; i += 256) atomicAdd(&hist[(seg[i] >> 16) & 255], 1);
    __syncthreads();

    int cnt_t = hist[tid];
    pfx[tid] = cnt_t;
    __syncthreads();
    for (int off = 1; off < 256; off <<= 1) {
        int t = (tid >= off) ? pfx[tid - off] : 0;
        __syncthreads();
        pfx[tid] += t;
        __syncthreads();
    }
    int excl = pfx[tid] - cnt_t;

    int node = b * 256 + tid;
    if (node < n) {
        rowptr[node] = outbase + excl;
        dis[node] = rsqrtf((float)(cnt_t + 1));  // +1 self loop
        if (node == n - 1) rowptr[n] = outbase + excl + cnt_t;
    }
    __syncthreads();
    pfx[tid] = excl;
    hist[tid] = 0;
    __syncthreads();
    for (int i = tid; i < sz; i += 256) {
        uint p = seg[i];
        int j = (p >> 16) & 255;
        int r = atomicAdd(&hist[j], 1);
        csr[outbase + pfx[j] + r] = (int)(p & 0xffffu);
    }
}

// standalone GEMM kernels (layers 2,3)
template <int COLS, bool F32IN>
__global__ __launch_bounds__(256) void gemm_mfma(const void* __restrict__ Xin,
                                                 const ushort* __restrict__ Wt,
                                                 ushort* __restrict__ Y, int n) {
    __shared__ char smem[(64 + COLS) * 136 * 2];
    gemm_body<COLS, F32IN>(Xin, Wt, Y, n, blockIdx.x, smem);
}

// ---------------------------------------------------------------------------
// agg128: out[v] = act( dv*(Σ dis[s]*H[s] + dv*H[v]) + b )
// One wave/node; 64 lanes per row (uint = 2 bf16 cols/lane). Edge index is
// wave-uniform (readlane -> SGPR) so row gathers use scalar base addressing.
// 16 independent gathers in flight.
// ---------------------------------------------------------------------------
template <bool RELU>
__global__ __launch_bounds__(256) void agg128(const ushort* __restrict__ H,
                                              const float* __restrict__ dis,
                                              const int* __restrict__ rowptr,
                                              const int* __restrict__ csr,
                                              const float* __restrict__ bias,
                                              uint* __restrict__ out, int n) {
    const int wid = blockIdx.x * 4 + (threadIdx.x >> 6);
    const int lane = threadIdx.x & 63;
    if (wid >= n) return;
    const int v = wid;
    const float dv = dis[v];
    const int e0 = rowptr[v];
    const int e1 = rowptr[v + 1];

    const uint* Hu = (const uint*)H;  // row = 64 uints
    uint h0 = Hu[(size_t)v * 64 + lane];
    float ax = dv * bf_lo(h0), ay = dv * bf_hi(h0);

    int e = e0;
    while (e < e1) {
        const int c = min(e1 - e, 64);
        int sidx = 0; float sw = 0.0f;
        if (lane < c) { sidx = csr[e + lane]; sw = dis[sidx]; }
        int j = 0;
        for (; j + 16 <= c; j += 16) {
            uint hv[16]; float w[16];
#pragma unroll
            for (int u = 0; u < 16; ++u) {
                int s = __builtin_amdgcn_readlane(sidx, j + u);
                w[u] = lane_bcast_f(sw, j + u);
                hv[u] = Hu[(size_t)s * 64 + lane];
            }
#pragma unroll
            for (int u = 0; u < 16; ++u) { ax += w[u] * bf_lo(hv[u]); ay += w[u] * bf_hi(hv[u]); }
        }
        for (; j + 4 <= c; j += 4) {
            uint hv[4]; float w[4];
#pragma unroll
            for (int u = 0; u < 4; ++u) {
                int s = __builtin_amdgcn_readlane(sidx, j + u);
                w[u] = lane_bcast_f(sw, j + u);
                hv[u] = Hu[(size_t)s * 64 + lane];
            }
#pragma unroll
            for (int u = 0; u < 4; ++u) { ax += w[u] * bf_lo(hv[u]); ay += w[u] * bf_hi(hv[u]); }
        }
        for (; j < c; ++j) {
            int s = __builtin_amdgcn_readlane(sidx, j);
            float w = lane_bcast_f(sw, j);
            uint hh = Hu[(size_t)s * 64 + lane];
            ax += w * bf_lo(hh); ay += w * bf_hi(hh);
        }
        e += c;
    }

    float2 b = ((const float2*)bias)[lane];
    float rx = dv * ax + b.x;
    float ry = dv * ay + b.y;
    if (RELU) { rx = fmaxf(rx, 0.f); ry = fmaxf(ry, 0.f); }
    uint packed = (uint)f2bf(rx) | ((uint)f2bf(ry) << 16);
    out[(size_t)v * 64 + lane] = packed;
}

// ---------------------------------------------------------------------------
// agg64 + row-normalize (final GCN layer), target_mlp fused as tail blocks.
// ---------------------------------------------------------------------------
__global__ __launch_bounds__(256) void agg64_final(const ushort* __restrict__ H,
                                                   const float* __restrict__ dis,
                                                   const int* __restrict__ rowptr,
                                                   const int* __restrict__ csr,
                                                   const float* __restrict__ bias,
                                                   float* __restrict__ out, int n, int agrid,
                                                   const float* __restrict__ y,
                                                   const float* __restrict__ gamma,
                                                   const float* __restrict__ beta,
                                                   const float* __restrict__ Wm1,
                                                   const float* __restrict__ bm1,
                                                   const float* __restrict__ Wm2,
                                                   const float* __restrict__ bm2,
                                                   float* __restrict__ out_y) {
    __shared__ float red[256];
    __shared__ float t1[128];
    __shared__ float s_mu, s_var;
    const int tid = threadIdx.x;

    if ((int)blockIdx.x >= agrid) {
        float yv = y[tid];
        red[tid] = yv;
        __syncthreads();
        for (int s = 128; s > 0; s >>= 1) {
            if (tid < s) red[tid] += red[tid + s];
            __syncthreads();
        }
        if (tid == 0) s_mu = red[0] * (1.0f / 256.0f);
        __syncthreads();
        float mu = s_mu;
        float d = yv - mu;
        red[tid] = d * d;
        __syncthreads();
        for (int s = 128; s > 0; s >>= 1) {
            if (tid < s) red[tid] += red[tid + s];
            __syncthreads();
        }
        if (tid == 0) s_var = red[0] * (1.0f / 256.0f);
        __syncthreads();

        const int row = blockIdx.x - agrid;
        float yb = (y[row] - mu) * rsqrtf(s_var + 1e-5f) * gamma[0] + beta[0];
        if (tid < 128) t1[tid] = fmaxf(yb * Wm1[tid] + bm1[tid], 0.0f);
        __syncthreads();
        if (tid < 64) {
            float acc = bm2[tid];
#pragma unroll 8
            for (int c = 0; c < 128; ++c) acc += t1[c] * Wm2[c * 64 + tid];
            float ss = acc * acc;
#pragma unroll
            for (int m = 1; m < 64; m <<= 1) ss += __shfl_xor(ss, m, 64);
            out_y[row * 64 + tid] = acc / fmaxf(sqrtf(ss), 1e-12f);
        }
        return;
    }

    const int wid = blockIdx.x * 4 + (tid >> 6);
    const int lane = tid & 63;
    if (wid >= n) return;
    const int v = wid;
    const float dv = dis[v];
    const int e0 = rowptr[v];
    const int e1 = rowptr[v + 1];

    float acc = dv * bf_lo((uint)H[(size_t)v * 64 + lane]);

    int e = e0;
    while (e < e1) {
        const int c = min(e1 - e, 64);
        int sidx = 0; float sw = 0.0f;
        if (lane < c) { sidx = csr[e + lane]; sw = dis[sidx]; }
        int j = 0;
        for (; j + 16 <= c; j += 16) {
            ushort hv[16]; float w[16];
#pragma unroll
            for (int u = 0; u < 16; ++u) {
                int s = __builtin_amdgcn_readlane(sidx, j + u);
                w[u] = lane_bcast_f(sw, j + u);
                hv[u] = H[(size_t)s * 64 + lane];
            }
#pragma unroll
            for (int u = 0; u < 16; ++u) acc += w[u] * bf_lo((uint)hv[u]);
        }
        for (; j < c; ++j) {
            int s = __builtin_amdgcn_readlane(sidx, j);
            float w = lane_bcast_f(sw, j);
            acc += w * bf_lo((uint)H[(size_t)s * 64 + lane]);
        }
        e += c;
    }

    float r = dv * acc + bias[lane];
    float ss = r * r;
#pragma unroll
    for (int m = 1; m < 64; m <<= 1) ss += __shfl_xor(ss, m, 64);
    r = r / fmaxf(sqrtf(ss), 1e-12f);
    out[(size_t)v * 64 + lane] = r;
}

// ---------------------------------------------------------------------------
extern "C" void kernel_launch(void* const* d_in, const int* in_sizes, int n_in,
                              void* d_out, int out_size, void* d_ws, size_t ws_size,
                              hipStream_t stream) {
    const float* x     = (const float*)d_in[0];
    const float* y     = (const float*)d_in[1];
    const int*   edge  = (const int*)d_in[2];
    const float* W1    = (const float*)d_in[3];
    const float* b1    = (const float*)d_in[4];
    const float* W2    = (const float*)d_in[5];
    const float* b2    = (const float*)d_in[6];
    const float* W3    = (const float*)d_in[7];
    const float* b3    = (const float*)d_in[8];
    const float* bng   = (const float*)d_in[9];
    const float* bnb   = (const float*)d_in[10];
    const float* Wm1   = (const float*)d_in[11];
    const float* bm1   = (const float*)d_in[12];
    const float* Wm2   = (const float*)d_in[13];
    const float* bm2   = (const float*)d_in[14];

    const int n = in_sizes[0] / 128;  // 50000
    const int E = in_sizes[2] / 2;    // 800000
    const int* src = edge;
    const int* dst = edge + E;

    const int nbuck = (n + 255) / 256;                 // 196
    const int cap = E / nbuck + E / nbuck / 4 + 1024;  // mean + 25% + slack

    size_t off = 0;
    auto carve = [&](size_t bytes) {
        size_t p = off;
        off = (off + bytes + 255) & ~(size_t)255;
        return p;
    };
    char* ws = (char*)d_ws;
    int*    gcur    = (int*)(ws + carve(256 * 4));
    uint*   part    = (uint*)(ws + carve((size_t)nbuck * cap * 4));
    int*    rowptr  = (int*)(ws + carve((size_t)(n + 1) * 4));
    int*    csr     = (int*)(ws + carve((size_t)E * 4));
    float*  dis     = (float*)(ws + carve((size_t)n * 4));
    ushort* wt1     = (ushort*)(ws + carve(128 * 128 * 2));
    ushort* wt2     = (ushort*)(ws + carve(128 * 128 * 2));
    ushort* wt3     = (ushort*)(ws + carve(64 * 128 * 2));
    ushort* bufA    = (ushort*)(ws + carve((size_t)n * 128 * 2));
    ushort* bufB    = (ushort*)(ws + carve((size_t)n * 128 * 2));
    ushort* bufC    = (ushort*)(ws + carve((size_t)n * 64 * 2));
    (void)ws_size; (void)n_in; (void)out_size;

    float* x_emb = (float*)d_out;
    float* y_emb = (float*)d_out + (size_t)n * 64;

    const int pblocks = (E + PCHUNK - 1) / PCHUNK;  // 196
    const int ggrid = (n + 63) / 64;                // 782
    const int agrid = (n + 3) / 4;                  // 12500

    hipMemsetAsync(gcur, 0, 256 * 4, stream);
    k_partition<<<pblocks + 160, 256, 0, stream>>>(src, dst, E, nbuck, cap, pblocks,
                                                   gcur, part, W1, W2, W3, wt1, wt2, wt3);
    // bucket sort (196 blocks) + gemm1 (782 blocks) run concurrently:
    // gemm1 depends only on x and wt1 (ready); sort feeds the aggs.
    k_sort_gemm1<<<nbuck + ggrid, 256, 0, stream>>>(part, gcur, nbuck, cap, n,
                                                    rowptr, dis, csr, x, wt1, bufA);

    agg128<true><<<agrid, 256, 0, stream>>>(bufA, dis, rowptr, csr, b1, (uint*)bufB, n);
    gemm_mfma<128, false><<<ggrid, 256, 0, stream>>>(bufB, wt2, bufA, n);
    agg128<true><<<agrid, 256, 0, stream>>>(bufA, dis, rowptr, csr, b2, (uint*)bufB, n);
    gemm_mfma<64, false><<<ggrid, 256, 0, stream>>>(bufB, wt3, bufC, n);
    agg64_final<<<agrid + 256, 256, 0, stream>>>(bufC, dis, rowptr, csr, b3, x_emb, n, agrid,
                                                 y, bng, bnb, Wm1, bm1, Wm2, bm2, y_emb);
}